// Round 1
// baseline (244.401 us; speedup 1.0000x reference)
//
#include <hip/hip_runtime.h>
#include <hip/hip_bf16.h>

// Problem constants (match reference setup_inputs)
constexpr int BB = 4;
constexpr int NN = 40960;
constexpr int KK = 16;
constexpr int DD = 8;
constexpr float BN_EPS = 1e-6f;

constexpr int STATS_BLOCKS = 512;
constexpr int STATS_THREADS = 256;

// ws layout (floats):
//   [0 .. STATS_BLOCKS*16)            per-block partials (8 sums, 8 sumsqs)
//   [STATS_BLOCKS*16 .. +80)          W' (BN-folded conv weight, 8x10)
//   [STATS_BLOCKS*16+80 .. +88)       b' (BN-folded bias, 8)

__global__ __launch_bounds__(STATS_THREADS) void locse_stats_kernel(
    const float* __restrict__ coords, const int* __restrict__ idx,
    const float* __restrict__ dist, const float* __restrict__ W,
    const float* __restrict__ bias, float* __restrict__ partials)
{
    __shared__ float sW[80];
    __shared__ float sb[8];
    if (threadIdx.x < 80) sW[threadIdx.x] = W[threadIdx.x];
    if (threadIdx.x < 8)  sb[threadIdx.x] = bias[threadIdx.x];
    __syncthreads();

    float sum[8] = {0.f, 0.f, 0.f, 0.f, 0.f, 0.f, 0.f, 0.f};
    float sq[8]  = {0.f, 0.f, 0.f, 0.f, 0.f, 0.f, 0.f, 0.f};

    const int total4 = BB * NN * (KK / 4);   // one thread handles 4 consecutive k
    for (int t = blockIdx.x * blockDim.x + threadIdx.x; t < total4;
         t += gridDim.x * blockDim.x) {
        const int k4 = t & 3;
        const int bn = t >> 2;               // b*NN + n
        const int b  = bn / NN;
        const float* cc = coords + (size_t)bn * 3;
        const float cx = cc[0], cy = cc[1], cz = cc[2];

        const int base = (bn << 4) + (k4 << 2);   // (b*N+n)*K + 4*k4 (16B aligned)
        const int4   j4 = *reinterpret_cast<const int4*>(idx + base);
        const float4 d4 = *reinterpret_cast<const float4*>(dist + base);
        const int   js[4] = {j4.x, j4.y, j4.z, j4.w};
        const float ds[4] = {d4.x, d4.y, d4.z, d4.w};

        #pragma unroll
        for (int kk = 0; kk < 4; ++kk) {
            const float* nc = coords + ((size_t)b * NN + js[kk]) * 3;
            const float nx = nc[0], ny = nc[1], nz = nc[2];
            const float c10[10] = {cx, cy, cz, nx, ny, nz,
                                   cx - nx, cy - ny, cz - nz, ds[kk]};
            #pragma unroll
            for (int d = 0; d < 8; ++d) {
                float h = sb[d];
                #pragma unroll
                for (int c = 0; c < 10; ++c) h = fmaf(sW[d * 10 + c], c10[c], h);
                sum[d] += h;
                sq[d]  += h * h;
            }
        }
    }

    // wave (64-lane) shuffle reduction for all 16 quantities
    #pragma unroll
    for (int v = 0; v < 8; ++v) {
        float s = sum[v], q = sq[v];
        #pragma unroll
        for (int off = 32; off > 0; off >>= 1) {
            s += __shfl_down(s, off, 64);
            q += __shfl_down(q, off, 64);
        }
        sum[v] = s; sq[v] = q;
    }

    __shared__ float wred[STATS_THREADS / 64][16];
    const int lane = threadIdx.x & 63;
    const int wid  = threadIdx.x >> 6;
    if (lane == 0) {
        #pragma unroll
        for (int v = 0; v < 8; ++v) {
            wred[wid][v]     = sum[v];
            wred[wid][8 + v] = sq[v];
        }
    }
    __syncthreads();
    if (threadIdx.x < 16) {
        float s = 0.f;
        #pragma unroll
        for (int w = 0; w < STATS_THREADS / 64; ++w) s += wred[w][threadIdx.x];
        partials[blockIdx.x * 16 + threadIdx.x] = s;
    }
}

__global__ __launch_bounds__(256) void locse_finalize_kernel(
    const float* __restrict__ partials, const float* __restrict__ W,
    const float* __restrict__ bias, const float* __restrict__ gamma,
    const float* __restrict__ beta, float* __restrict__ wp,
    float* __restrict__ bp)
{
    const int t = threadIdx.x;
    const int c = t & 15;
    float acc = 0.f;
    for (int i = t >> 4; i < STATS_BLOCKS; i += 16) acc += partials[i * 16 + c];

    __shared__ float red[256];
    __shared__ float tot[16];
    __shared__ float scale_s[8];
    red[t] = acc;
    __syncthreads();
    if (t < 16) {
        float s = 0.f;
        #pragma unroll
        for (int i = 0; i < 16; ++i) s += red[i * 16 + t];
        tot[t] = s;
    }
    __syncthreads();
    if (t < 8) {
        const float cnt  = (float)BB * (float)NN * (float)KK;
        const float mean = tot[t] / cnt;
        const float var  = tot[8 + t] / cnt - mean * mean;
        const float sc   = gamma[t] * rsqrtf(var + BN_EPS);
        scale_s[t] = sc;
        bp[t] = fmaf(bias[t] - mean, sc, beta[t]);   // (b - mean)*sc + beta
    }
    __syncthreads();
    if (t < 80) wp[t] = W[t] * scale_s[t / 10];
}

__global__ __launch_bounds__(256) void locse_out_kernel(
    const float* __restrict__ coords, const float* __restrict__ features,
    const int* __restrict__ idx, const float* __restrict__ dist,
    const float* __restrict__ wp, const float* __restrict__ bp,
    float* __restrict__ out)
{
    __shared__ float sW[80];
    __shared__ float sb[8];
    if (threadIdx.x < 80) sW[threadIdx.x] = wp[threadIdx.x];
    if (threadIdx.x < 8)  sb[threadIdx.x] = bp[threadIdx.x];
    __syncthreads();

    const int total4 = BB * NN * (KK / 4);
    for (int t = blockIdx.x * blockDim.x + threadIdx.x; t < total4;
         t += gridDim.x * blockDim.x) {
        const int k4 = t & 3;
        const int bn = t >> 2;
        const int n  = bn % NN;
        const int b  = bn / NN;
        const float* cc = coords + (size_t)bn * 3;
        const float cx = cc[0], cy = cc[1], cz = cc[2];

        const int base = (bn << 4) + (k4 << 2);
        const int4   j4 = *reinterpret_cast<const int4*>(idx + base);
        const float4 d4 = *reinterpret_cast<const float4*>(dist + base);
        const int   js[4] = {j4.x, j4.y, j4.z, j4.w};
        const float ds[4] = {d4.x, d4.y, d4.z, d4.w};

        float hv[8][4];
        #pragma unroll
        for (int kk = 0; kk < 4; ++kk) {
            const float* nc = coords + ((size_t)b * NN + js[kk]) * 3;
            const float nx = nc[0], ny = nc[1], nz = nc[2];
            const float c10[10] = {cx, cy, cz, nx, ny, nz,
                                   cx - nx, cy - ny, cz - nz, ds[kk]};
            #pragma unroll
            for (int d = 0; d < 8; ++d) {
                float h = sb[d];
                #pragma unroll
                for (int c = 0; c < 10; ++c) h = fmaf(sW[d * 10 + c], c10[c], h);
                hv[d][kk] = fmaxf(h, 0.f);
            }
        }

        // out[b, ch, n, k]: base offset for (b, ch=0, n, k4*4)
        const size_t outn = (size_t)b * 16 * NN * KK + (size_t)n * KK + (k4 << 2);
        #pragma unroll
        for (int d = 0; d < 8; ++d) {
            *reinterpret_cast<float4*>(out + outn + (size_t)d * NN * KK) =
                make_float4(hv[d][0], hv[d][1], hv[d][2], hv[d][3]);
        }
        #pragma unroll
        for (int d = 0; d < 8; ++d) {
            const float f = features[((size_t)b * DD + d) * NN + n];
            *reinterpret_cast<float4*>(out + outn + (size_t)(8 + d) * NN * KK) =
                make_float4(f, f, f, f);
        }
    }
}

extern "C" void kernel_launch(void* const* d_in, const int* in_sizes, int n_in,
                              void* d_out, int out_size, void* d_ws, size_t ws_size,
                              hipStream_t stream) {
    const float* coords   = (const float*)d_in[0];
    const float* features = (const float*)d_in[1];
    const int*   idx      = (const int*)d_in[2];
    const float* dist     = (const float*)d_in[3];
    const float* W        = (const float*)d_in[4];
    const float* bias     = (const float*)d_in[5];
    const float* gamma    = (const float*)d_in[6];
    const float* beta     = (const float*)d_in[7];
    float* out = (float*)d_out;

    float* wsf      = (float*)d_ws;
    float* partials = wsf;
    float* wp       = wsf + STATS_BLOCKS * 16;
    float* bp       = wp + 80;

    locse_stats_kernel<<<dim3(STATS_BLOCKS), dim3(STATS_THREADS), 0, stream>>>(
        coords, idx, dist, W, bias, partials);
    locse_finalize_kernel<<<dim3(1), dim3(256), 0, stream>>>(
        partials, W, bias, gamma, beta, wp, bp);

    const int total4 = BB * NN * (KK / 4);
    const int blocks = (total4 + 255) / 256;   // 2560
    locse_out_kernel<<<dim3(blocks), dim3(256), 0, stream>>>(
        coords, features, idx, dist, wp, bp, out);
}